// Round 1
// baseline (109.176 us; speedup 1.0000x reference)
//
#include <hip/hip_runtime.h>

// 8-qubit batched statevector sim: one wave per batch element.
// idx = lane*4 + r ; bit p of idx: p in {0,1} -> r bits, p in 2..7 -> lane bit (p-2).
// Qubit q <-> bit (7-q).

static __device__ __forceinline__ float rlane(float v, int src) {
    return __int_as_float(__builtin_amdgcn_readlane(__float_as_int(v), src));
}

__global__ __launch_bounds__(256) void qsim_kernel(const float* __restrict__ X,
                                                   const float* __restrict__ W,
                                                   float* __restrict__ out,
                                                   int B) {
    const int lane = threadIdx.x & 63;
    const int b = blockIdx.x * 4 + (threadIdx.x >> 6);
    if (b >= B) return;

    // ---- fused H->RZ->RY first column u_q, computed in lane q (q = lane&7) ----
    const int q8 = lane & 7;
    const float tz = 0.5f * X[b * 16 + 2 * q8];
    const float ty = 0.5f * X[b * 16 + 2 * q8 + 1];
    float cz, sz, cy, sy;
    __sincosf(tz, &sz, &cz);
    __sincosf(ty, &sy, &cy);
    // u0 = ((cy-sy)cz, -(cy+sy)sz), u1 = ((cy+sy)cz, (cy-sy)sz)   [1/sqrt2 folded out]
    const float u0r = (cy - sy) * cz;
    const float u0i = -(cy + sy) * sz;
    const float u1r = (cy + sy) * cz;
    const float u1i = (cy - sy) * sz;

    // ---- CRX trig: lane g (<56) holds cos/sin of 0.5*W[1+i, j] ----
    float gcv = 1.0f, gsv = 0.0f;
    if (lane < 56) {
        const int i = lane / 7;
        const int jj = lane - 7 * i;
        const int j = jj + (jj >= i ? 1 : 0);
        const float h = 0.5f * W[(1 + i) * 72 + j];
        __sincosf(h, &gsv, &gcv);
    }

    // ---- build product state ----
    float Pr = 1.0f, Pi = 0.0f;
#pragma unroll
    for (int p = 7; p >= 2; --p) {
        const int q = 7 - p;  // qubit at bit p
        const float a0r = rlane(u0r, q), a0i = rlane(u0i, q);
        const float a1r = rlane(u1r, q), a1i = rlane(u1i, q);
        const int bit = (lane >> (p - 2)) & 1;
        const float vr = bit ? a1r : a0r;
        const float vi = bit ? a1i : a0i;
        const float nr = Pr * vr - Pi * vi;
        const float ni = Pr * vi + Pi * vr;
        Pr = nr; Pi = ni;
    }
    const float x0r = rlane(u0r, 6), x0i = rlane(u0i, 6);  // qubit6 (bit1)
    const float x1r = rlane(u1r, 6), x1i = rlane(u1i, 6);
    const float y0r = rlane(u0r, 7), y0i = rlane(u0i, 7);  // qubit7 (bit0)
    const float y1r = rlane(u1r, 7), y1i = rlane(u1i, 7);

    float ar[4], ai[4];
    {
        float mr[4], mi[4];  // m[r] = u6[bit1(r)] * u7[bit0(r)]
        mr[0] = x0r * y0r - x0i * y0i;  mi[0] = x0r * y0i + x0i * y0r;
        mr[1] = x0r * y1r - x0i * y1i;  mi[1] = x0r * y1i + x0i * y1r;
        mr[2] = x1r * y0r - x1i * y0i;  mi[2] = x1r * y0i + x1i * y0r;
        mr[3] = x1r * y1r - x1i * y1i;  mi[3] = x1r * y1i + x1i * y1r;
#pragma unroll
        for (int r = 0; r < 4; ++r) {
            ar[r] = Pr * mr[r] - Pi * mi[r];
            ai[r] = Pr * mi[r] + Pi * mr[r];
        }
    }

    // ---- CRZ ring (all 8 gates fused into one diagonal phase) ----
    // pairs (ctrl bit, tgt bit, w): (7,6,w0)(6,5,w1)(5,4,w2)(4,3,w3)(3,2,w4)(2,1,w5)(1,0,w6)(0,7,w7)
    {
        const float w0 = W[0], w1 = W[1], w2 = W[2], w3 = W[3];
        const float w4 = W[4], w5 = W[5], w6 = W[6], w7 = W[7];
        const int lb2 = lane & 1, lb3 = (lane >> 1) & 1, lb4 = (lane >> 2) & 1;
        const int lb5 = (lane >> 3) & 1, lb6 = (lane >> 4) & 1, lb7 = (lane >> 5) & 1;
        float phiL = 0.0f;
        phiL += lb7 ? (lb6 ? w0 : -w0) : 0.0f;
        phiL += lb6 ? (lb5 ? w1 : -w1) : 0.0f;
        phiL += lb5 ? (lb4 ? w2 : -w2) : 0.0f;
        phiL += lb4 ? (lb3 ? w3 : -w3) : 0.0f;
        phiL += lb3 ? (lb2 ? w4 : -w4) : 0.0f;
        const float t5 = lb2 ? w5 : 0.0f;   // ctrl bit2; tgt-bit1 sign applied per r
        const float t7 = lb7 ? w7 : -w7;    // added when bit0(r)=1
#pragma unroll
        for (int r = 0; r < 4; ++r) {
            const int bit1 = (r >> 1) & 1, bit0 = r & 1;
            float phi = phiL + (bit1 ? t5 : -t5);
            if (bit1) phi += bit0 ? w6 : -w6;
            if (bit0) phi += t7;
            phi *= 0.5f;
            float sp, cp;
            __sincosf(phi, &sp, &cp);
            const float nr = ar[r] * cp - ai[r] * sp;
            const float ni = ar[r] * sp + ai[r] * cp;
            ar[r] = nr; ai[r] = ni;
        }
    }

    // ---- 56 CRX gates, reference order (i outer, j inner, j!=i) ----
    // new = c*a - i*s*partner on ctrl=1; symmetric in target bit.
#pragma unroll
    for (int i = 0; i < 8; ++i) {
#pragma unroll
        for (int j = 0; j < 8; ++j) {
            if (j == i) continue;
            const int g = i * 7 + (j < i ? j : j - 1);
            const int pc = 7 - i;
            const int pt = 7 - j;
            const float c = rlane(gcv, g);
            const float s = rlane(gsv, g);
            float ce = c, se = s;
            if (pc >= 2) {  // control is a lane bit: fold into coefficients
                const int ctrl = (lane >> (pc - 2)) & 1;
                ce = ctrl ? c : 1.0f;
                se = ctrl ? s : 0.0f;
            }
            if (pt >= 2) {  // target partner across lanes
                const int m = 1 << (pt - 2);
#pragma unroll
                for (int r = 0; r < 4; ++r) {
                    if (pc < 2 && !((r >> pc) & 1)) continue;  // ctrl reg-bit clear
                    const float prr = __shfl_xor(ar[r], m, 64);
                    const float pii = __shfl_xor(ai[r], m, 64);
                    const float cc = (pc >= 2) ? ce : c;
                    const float ss = (pc >= 2) ? se : s;
                    ar[r] = cc * ar[r] + ss * pii;
                    ai[r] = cc * ai[r] - ss * prr;
                }
            } else {  // target partner is a register
                float oar[4], oai[4];
#pragma unroll
                for (int r = 0; r < 4; ++r) { oar[r] = ar[r]; oai[r] = ai[r]; }
#pragma unroll
                for (int r = 0; r < 4; ++r) {
                    if (pc < 2 && !((r >> pc) & 1)) continue;
                    const int rp = r ^ (1 << pt);
                    const float cc = (pc >= 2) ? ce : c;
                    const float ss = (pc >= 2) ? se : s;
                    ar[r] = cc * oar[r] + ss * oai[rp];
                    ai[r] = cc * oai[r] - ss * oar[rp];
                }
            }
        }
    }

    // ---- probabilities + all 8 <Z_q> in one signed butterfly ----
    const float p0 = ar[0] * ar[0] + ai[0] * ai[0];
    const float p1 = ar[1] * ar[1] + ai[1] * ai[1];
    const float p2 = ar[2] * ar[2] + ai[2] * ai[2];
    const float p3 = ar[3] * ar[3] + ai[3] * ai[3];
    const float s01 = p0 + p1, s23 = p2 + p3;
    float A = s01 + s23;           // plain sum
    float e6 = s01 - s23;          // qubit6 (bit1 sign)
    float e7 = (p0 - p1) + (p2 - p3);  // qubit7 (bit0 sign)
    float D[6];
#pragma unroll
    for (int k = 0; k < 6; ++k) {
        const int m = 1 << k;
        const float t = __shfl_xor(A, m, 64);
        D[k] = A - t;   // signed by lane bit k (bit p=k+2 -> qubit 5-k)
        A = A + t;
#pragma unroll
        for (int kk = 0; kk < k; ++kk) D[kk] += __shfl_xor(D[kk], m, 64);
        e6 += __shfl_xor(e6, m, 64);
        e7 += __shfl_xor(e7, m, 64);
    }
    if (lane == 0) {
        const float sc = 1.0f / 256.0f;  // (1/sqrt2)^8 squared, folded out of u's
        float* o = out + b * 8;
        o[0] = D[5] * sc;
        o[1] = D[4] * sc;
        o[2] = D[3] * sc;
        o[3] = D[2] * sc;
        o[4] = D[1] * sc;
        o[5] = D[0] * sc;
        o[6] = e6 * sc;
        o[7] = e7 * sc;
    }
}

extern "C" void kernel_launch(void* const* d_in, const int* in_sizes, int n_in,
                              void* d_out, int out_size, void* d_ws, size_t ws_size,
                              hipStream_t stream) {
    const float* X = (const float*)d_in[0];
    const float* W = (const float*)d_in[1];
    float* out = (float*)d_out;
    const int B = in_sizes[0] / 16;  // 2*N floats per row
    const int blocks = (B + 3) / 4;  // 4 waves (batch elems) per 256-thread block
    qsim_kernel<<<blocks, 256, 0, stream>>>(X, W, out, B);
}

// Round 2
// 79.246 us; speedup vs baseline: 1.3777x; 1.3777x over previous
//
#include <hip/hip_runtime.h>

// 8-qubit batched statevector sim, layout v2:
//   16 amps per lane (regs r=0..15), 16 lanes per element, 4 elements per wave.
//   amp index idx = s*16 + r  (s = lane&15 sublane, g = lane>>4 group/elem).
//   bit p of idx: p in {0..3} -> bit p of r ; p in {4..7} -> bit (p-4) of s.
//   qubit q <-> bit (7-q):  q0..q3 -> s bits 3..0 ; q4..q7 -> r bits 3..0.
// Cross-lane xor1/xor2 via DPP quad_perm (VALU), xor4/xor8 via ds_swizzle.

static __device__ __forceinline__ float rlane(float v, int src) {
    return __int_as_float(__builtin_amdgcn_readlane(__float_as_int(v), src));
}
static __device__ __forceinline__ float dppx1(float x) {  // lane ^ 1: quad_perm [1,0,3,2]
    return __int_as_float(__builtin_amdgcn_update_dpp(0, __float_as_int(x), 0xB1, 0xF, 0xF, true));
}
static __device__ __forceinline__ float dppx2(float x) {  // lane ^ 2: quad_perm [2,3,0,1]
    return __int_as_float(__builtin_amdgcn_update_dpp(0, __float_as_int(x), 0x4E, 0xF, 0xF, true));
}

__global__ __launch_bounds__(256, 4) void qsim_kernel(const float* __restrict__ X,
                                                      const float* __restrict__ W,
                                                      float* __restrict__ out,
                                                      int B) {
    const int lane = threadIdx.x & 63;
    const int g = lane >> 4;   // element slot in wave
    const int s = lane & 15;   // sublane within element
    const int b = (blockIdx.x * 4 + (threadIdx.x >> 6)) * 4 + g;
    const bool active = (b < B);

    // ---- CRX trig: lane gi (<56) holds cos/sin of 0.5*W[1+i, j] (wave-shared) ----
    float gcv = 1.0f, gsv = 0.0f;
    if (lane < 56) {
        const int i = lane / 7;
        const int jj = lane - 7 * i;
        const int j = jj + (jj >= i ? 1 : 0);
        const float h = 0.5f * W[(1 + i) * 72 + j];
        __sincosf(h, &gsv, &gcv);
    }

    // ---- per-qubit fused H->RZ->RY first column (sublane q computes qubit q) ----
    float u0r, u0i, u1r, u1i;
    {
        const int q = s & 7;
        float2 xq = active ? ((const float2*)X)[b * 8 + q] : make_float2(0.f, 0.f);
        float cz, sz, cy, sy;
        __sincosf(0.5f * xq.x, &sz, &cz);
        __sincosf(0.5f * xq.y, &sy, &cy);
        u0r = (cy - sy) * cz;  u0i = -(cy + sy) * sz;
        u1r = (cy + sy) * cz;  u1i = (cy - sy) * sz;
    }

    // ---- product state ----
    // lane part: qubits 0..3, bit = s bit (3-q)
    float Pr = 1.0f, Pi = 0.0f;
#pragma unroll
    for (int q = 0; q < 4; ++q) {
        const int src = (g << 4) + q;
        const float a0r = __shfl(u0r, src, 64), a0i = __shfl(u0i, src, 64);
        const float a1r = __shfl(u1r, src, 64), a1i = __shfl(u1i, src, 64);
        const int bit = (s >> (3 - q)) & 1;
        const float vr = bit ? a1r : a0r;
        const float vi = bit ? a1i : a0i;
        const float nr = Pr * vr - Pi * vi;
        const float ni = Pr * vi + Pi * vr;
        Pr = nr; Pi = ni;
    }
    // reg part: qubits 4..7 (r bits 3..0), fetch both columns of each
    float w0r[4], w0i[4], w1r[4], w1i[4];
#pragma unroll
    for (int q = 4; q < 8; ++q) {
        const int src = (g << 4) + q;
        w0r[q - 4] = __shfl(u0r, src, 64);  w0i[q - 4] = __shfl(u0i, src, 64);
        w1r[q - 4] = __shfl(u1r, src, 64);  w1i[q - 4] = __shfl(u1i, src, 64);
    }
    float ar[16], ai[16];
    {
        // doubling build over r bits 3,2,1,0 (qubits 4,5,6,7)
        float t1r[2], t1i[2];            // index b3
        t1r[0] = w0r[0]; t1i[0] = w0i[0];
        t1r[1] = w1r[0]; t1i[1] = w1i[0];
        float t2r[4], t2i[4];            // index (b3<<1)|b2
#pragma unroll
        for (int h = 0; h < 2; ++h) {
            t2r[h * 2 + 0] = t1r[h] * w0r[1] - t1i[h] * w0i[1];
            t2i[h * 2 + 0] = t1r[h] * w0i[1] + t1i[h] * w0r[1];
            t2r[h * 2 + 1] = t1r[h] * w1r[1] - t1i[h] * w1i[1];
            t2i[h * 2 + 1] = t1r[h] * w1i[1] + t1i[h] * w1r[1];
        }
        float t3r[8], t3i[8];            // index (b3<<2)|(b2<<1)|b1
#pragma unroll
        for (int h = 0; h < 4; ++h) {
            t3r[h * 2 + 0] = t2r[h] * w0r[2] - t2i[h] * w0i[2];
            t3i[h * 2 + 0] = t2r[h] * w0i[2] + t2i[h] * w0r[2];
            t3r[h * 2 + 1] = t2r[h] * w1r[2] - t2i[h] * w1i[2];
            t3i[h * 2 + 1] = t2r[h] * w1i[2] + t2i[h] * w1r[2];
        }
#pragma unroll
        for (int h = 0; h < 8; ++h) {
            const float m0r = t3r[h] * w0r[3] - t3i[h] * w0i[3];
            const float m0i = t3r[h] * w0i[3] + t3i[h] * w0r[3];
            const float m1r = t3r[h] * w1r[3] - t3i[h] * w1i[3];
            const float m1i = t3r[h] * w1i[3] + t3i[h] * w1r[3];
            ar[h * 2 + 0] = Pr * m0r - Pi * m0i;
            ai[h * 2 + 0] = Pr * m0i + Pi * m0r;
            ar[h * 2 + 1] = Pr * m1r - Pi * m1i;
            ai[h * 2 + 1] = Pr * m1i + Pi * m1r;
        }
    }

    // ---- CRZ ring fused into one diagonal phase per amp ----
    // pairs (ctrl bit, tgt bit, w): (7,6,w0)(6,5,w1)(5,4,w2)(4,3,w3)(3,2,w4)(2,1,w5)(1,0,w6)(0,7,w7)
    {
        const float w0 = W[0], w1 = W[1], w2 = W[2], w3 = W[3];
        const float w4 = W[4], w5 = W[5], w6 = W[6], w7 = W[7];
        const int b7 = (s >> 3) & 1, b6 = (s >> 2) & 1, b5 = (s >> 1) & 1, b4 = s & 1;
        float phiS = 0.0f;
        phiS += b7 ? (b6 ? w0 : -w0) : 0.0f;
        phiS += b6 ? (b5 ? w1 : -w1) : 0.0f;
        phiS += b5 ? (b4 ? w2 : -w2) : 0.0f;
        const float term3 = b4 ? w3 : 0.0f;   // pair (4,3): sign by r bit3
        const float term7 = b7 ? w7 : -w7;    // pair (0,7): added when r bit0 = 1
#pragma unroll
        for (int r = 0; r < 16; ++r) {
            const int b3 = (r >> 3) & 1, b2 = (r >> 2) & 1, b1 = (r >> 1) & 1, b0 = r & 1;
            float phi = phiS + (b3 ? term3 : -term3);
            if (b3) phi += b2 ? w4 : -w4;
            if (b2) phi += b1 ? w5 : -w5;
            if (b1) phi += b0 ? w6 : -w6;
            if (b0) phi += term7;
            float sp, cp;
            __sincosf(0.5f * phi, &sp, &cp);
            const float nr = ar[r] * cp - ai[r] * sp;
            const float ni = ar[r] * sp + ai[r] * cp;
            ar[r] = nr; ai[r] = ni;
        }
    }

    // ---- 56 CRX gates in reference order ----
#pragma unroll
    for (int i = 0; i < 8; ++i) {
#pragma unroll
        for (int j = 0; j < 8; ++j) {
            if (j == i) continue;
            const int gi = i * 7 + (j < i ? j : j - 1);
            const float c = rlane(gcv, gi);
            const float sn = rlane(gsv, gi);
            const int pc = 7 - i, pt = 7 - j;
            float ce, se;
            if (pc >= 4) {  // control is a sublane bit: fold into coefficients
                const int ctrl = (s >> (pc - 4)) & 1;
                ce = ctrl ? c : 1.0f;
                se = ctrl ? sn : 0.0f;
            } else {        // control is a reg bit: honest half-work
                ce = c; se = sn;
            }
            if (pt >= 4) {  // target across sublanes
                const int ms = 1 << (pt - 4);
#pragma unroll
                for (int r = 0; r < 16; ++r) {
                    if (pc < 4 && !((r >> pc) & 1)) continue;
                    float prr, pii;
                    if (ms == 1)      { prr = dppx1(ar[r]); pii = dppx1(ai[r]); }
                    else if (ms == 2) { prr = dppx2(ar[r]); pii = dppx2(ai[r]); }
                    else              { prr = __shfl_xor(ar[r], ms, 64);
                                        pii = __shfl_xor(ai[r], ms, 64); }
                    ar[r] = ce * ar[r] + se * pii;
                    ai[r] = ce * ai[r] - se * prr;
                }
            } else {        // target is a reg bit: in-register pair update
                const int mt = 1 << pt;
#pragma unroll
                for (int r = 0; r < 16; ++r) {
                    if (r & mt) continue;
                    if (pc < 4 && !((r >> pc) & 1)) continue;
                    const int rp = r | mt;
                    const float tr = ar[r],  ti = ai[r];
                    const float ur = ar[rp], ui = ai[rp];
                    ar[r]  = ce * tr + se * ui;
                    ai[r]  = ce * ti - se * ur;
                    ar[rp] = ce * ur + se * ti;
                    ai[rp] = ce * ui - se * tr;
                }
            }
        }
    }

    // ---- probabilities + all 8 <Z_q> ----
    float p[16];
#pragma unroll
    for (int r = 0; r < 16; ++r) p[r] = ar[r] * ar[r] + ai[r] * ai[r];
    // in-lane tree over r bits: bit0->q7, bit1->q6, bit2->q5, bit3->q4
    float s8[8], E7 = 0.0f;
#pragma unroll
    for (int k = 0; k < 8; ++k) { s8[k] = p[2 * k] + p[2 * k + 1]; E7 += p[2 * k] - p[2 * k + 1]; }
    float s4[4], E6 = 0.0f;
#pragma unroll
    for (int k = 0; k < 4; ++k) { s4[k] = s8[2 * k] + s8[2 * k + 1]; E6 += s8[2 * k] - s8[2 * k + 1]; }
    float s2a[2], E5 = 0.0f;
#pragma unroll
    for (int k = 0; k < 2; ++k) { s2a[k] = s4[2 * k] + s4[2 * k + 1]; E5 += s4[2 * k] - s4[2 * k + 1]; }
    float A  = s2a[0] + s2a[1];
    float E4 = s2a[0] - s2a[1];
    // cross-sublane signed butterfly over s bits l (qubit 3-l)
    float D0, D1, D2, D3;
    { const float t = dppx1(A); D0 = A - t; A += t;
      E4 += dppx1(E4); E5 += dppx1(E5); E6 += dppx1(E6); E7 += dppx1(E7); }
    { const float t = dppx2(A); D1 = A - t; A += t;
      D0 += dppx2(D0);
      E4 += dppx2(E4); E5 += dppx2(E5); E6 += dppx2(E6); E7 += dppx2(E7); }
    { const float t = __shfl_xor(A, 4, 64); D2 = A - t; A += t;
      D0 += __shfl_xor(D0, 4, 64); D1 += __shfl_xor(D1, 4, 64);
      E4 += __shfl_xor(E4, 4, 64); E5 += __shfl_xor(E5, 4, 64);
      E6 += __shfl_xor(E6, 4, 64); E7 += __shfl_xor(E7, 4, 64); }
    { const float t = __shfl_xor(A, 8, 64); D3 = A - t;
      D0 += __shfl_xor(D0, 8, 64); D1 += __shfl_xor(D1, 8, 64); D2 += __shfl_xor(D2, 8, 64);
      E4 += __shfl_xor(E4, 8, 64); E5 += __shfl_xor(E5, 8, 64);
      E6 += __shfl_xor(E6, 8, 64); E7 += __shfl_xor(E7, 8, 64); }

    if (s == 0 && active) {
        const float sc = 1.0f / 256.0f;  // (1/sqrt2)^8 squared, folded out of u's
        float* o = out + b * 8;
        o[0] = D3 * sc;  // qubit0 <- s bit3
        o[1] = D2 * sc;
        o[2] = D1 * sc;
        o[3] = D0 * sc;
        o[4] = E4 * sc;  // qubit4 <- r bit3
        o[5] = E5 * sc;
        o[6] = E6 * sc;
        o[7] = E7 * sc;
    }
}

extern "C" void kernel_launch(void* const* d_in, const int* in_sizes, int n_in,
                              void* d_out, int out_size, void* d_ws, size_t ws_size,
                              hipStream_t stream) {
    const float* X = (const float*)d_in[0];
    const float* W = (const float*)d_in[1];
    float* out = (float*)d_out;
    const int B = in_sizes[0] / 16;       // 2*N floats per row
    const int blocks = (B + 15) / 16;     // 4 waves x 4 elements per 256-thread block
    qsim_kernel<<<blocks, 256, 0, stream>>>(X, W, out, B);
}

// Round 3
// 78.176 us; speedup vs baseline: 1.3965x; 1.0137x over previous
//
#include <hip/hip_runtime.h>

// 8-qubit batched statevector sim, layout v3 (all cross-lane via DPP):
//   16 amps per lane (regs r=0..15), 16 lanes per element, 4 elements per wave.
//   amp index idx = s*16 + r  (s = lane&15 sublane, g = lane>>4 group/elem).
//   bit p of idx: p in {0..3} -> bit p of r ; p in {4..7} -> bit (p-4) of s.
//   qubit q <-> bit (7-q):  q0..q3 -> s bits 3..0 ; q4..q7 -> r bits 3..0.
// Cross-lane xor1/xor2: quad_perm. xor4: half_mirror(l^7) o quad_perm(l^3).
// xor8: row_ror:8 (rotation by 8 in a 16-ring == xor 8). Zero DS in hot loop.

static __device__ __forceinline__ float rlane(float v, int src) {
    return __int_as_float(__builtin_amdgcn_readlane(__float_as_int(v), src));
}
template <int CTRL>
static __device__ __forceinline__ float dppf(float x) {
    return __int_as_float(__builtin_amdgcn_update_dpp(0, __float_as_int(x), CTRL, 0xF, 0xF, true));
}
static __device__ __forceinline__ float xor1f(float x) { return dppf<0xB1>(x); }   // quad_perm [1,0,3,2]
static __device__ __forceinline__ float xor2f(float x) { return dppf<0x4E>(x); }   // quad_perm [2,3,0,1]
static __device__ __forceinline__ float xor4f(float x) { return dppf<0x1B>(dppf<0x141>(x)); } // (l^7)^3
static __device__ __forceinline__ float xor8f(float x) { return dppf<0x128>(x); }  // row_ror:8

__global__ __launch_bounds__(256, 4) void qsim_kernel(const float* __restrict__ X,
                                                      const float* __restrict__ W,
                                                      float* __restrict__ out,
                                                      int B) {
    const int lane = threadIdx.x & 63;
    const int g = lane >> 4;   // element slot in wave
    const int s = lane & 15;   // sublane within element
    const int b = (blockIdx.x * 4 + (threadIdx.x >> 6)) * 4 + g;
    const bool active = (b < B);
    const int bc = active ? b : (B - 1);   // clamped for loads; keep all lanes alive for DPP

    // ---- CRX trig: lane gi (<56) holds cos/sin of 0.5*W[1+i, j] (wave-shared) ----
    float gcv = 1.0f, gsv = 0.0f;
    if (lane < 56) {
        const int i = lane / 7;
        const int jj = lane - 7 * i;
        const int j = jj + (jj >= i ? 1 : 0);
        const float h = 0.5f * W[(1 + i) * 72 + j];
        __sincosf(h, &gsv, &gcv);
    }

    // ---- per-qubit fused H->RZ->RY first column (sublane q computes qubit q) ----
    float u0r, u0i, u1r, u1i;
    {
        const int q = s & 7;
        float2 xq = ((const float2*)X)[bc * 8 + q];
        float cz, sz, cy, sy;
        __sincosf(0.5f * xq.x, &sz, &cz);
        __sincosf(0.5f * xq.y, &sy, &cy);
        u0r = (cy - sy) * cz;  u0i = -(cy + sy) * sz;
        u1r = (cy + sy) * cz;  u1i = (cy - sy) * sz;
    }

    // ---- product state ----
    // lane part: qubits 0..3, bit = s bit (3-q)
    float Pr = 1.0f, Pi = 0.0f;
#pragma unroll
    for (int q = 0; q < 4; ++q) {
        const int src = (g << 4) + q;
        const float a0r = __shfl(u0r, src, 64), a0i = __shfl(u0i, src, 64);
        const float a1r = __shfl(u1r, src, 64), a1i = __shfl(u1i, src, 64);
        const int bit = (s >> (3 - q)) & 1;
        const float vr = bit ? a1r : a0r;
        const float vi = bit ? a1i : a0i;
        const float nr = Pr * vr - Pi * vi;
        const float ni = Pr * vi + Pi * vr;
        Pr = nr; Pi = ni;
    }
    // reg part: qubits 4..7 (r bits 3..0), fetch both columns of each
    float w0r[4], w0i[4], w1r[4], w1i[4];
#pragma unroll
    for (int q = 4; q < 8; ++q) {
        const int src = (g << 4) + q;
        w0r[q - 4] = __shfl(u0r, src, 64);  w0i[q - 4] = __shfl(u0i, src, 64);
        w1r[q - 4] = __shfl(u1r, src, 64);  w1i[q - 4] = __shfl(u1i, src, 64);
    }
    float ar[16], ai[16];
    {
        // doubling build over r bits 3,2,1,0 (qubits 4,5,6,7)
        float t1r[2], t1i[2];
        t1r[0] = w0r[0]; t1i[0] = w0i[0];
        t1r[1] = w1r[0]; t1i[1] = w1i[0];
        float t2r[4], t2i[4];
#pragma unroll
        for (int h = 0; h < 2; ++h) {
            t2r[h * 2 + 0] = t1r[h] * w0r[1] - t1i[h] * w0i[1];
            t2i[h * 2 + 0] = t1r[h] * w0i[1] + t1i[h] * w0r[1];
            t2r[h * 2 + 1] = t1r[h] * w1r[1] - t1i[h] * w1i[1];
            t2i[h * 2 + 1] = t1r[h] * w1i[1] + t1i[h] * w1r[1];
        }
        float t3r[8], t3i[8];
#pragma unroll
        for (int h = 0; h < 4; ++h) {
            t3r[h * 2 + 0] = t2r[h] * w0r[2] - t2i[h] * w0i[2];
            t3i[h * 2 + 0] = t2r[h] * w0i[2] + t2i[h] * w0r[2];
            t3r[h * 2 + 1] = t2r[h] * w1r[2] - t2i[h] * w1i[2];
            t3i[h * 2 + 1] = t2r[h] * w1i[2] + t2i[h] * w1r[2];
        }
#pragma unroll
        for (int h = 0; h < 8; ++h) {
            const float m0r = t3r[h] * w0r[3] - t3i[h] * w0i[3];
            const float m0i = t3r[h] * w0i[3] + t3i[h] * w0r[3];
            const float m1r = t3r[h] * w1r[3] - t3i[h] * w1i[3];
            const float m1i = t3r[h] * w1i[3] + t3i[h] * w1r[3];
            ar[h * 2 + 0] = Pr * m0r - Pi * m0i;
            ai[h * 2 + 0] = Pr * m0i + Pi * m0r;
            ar[h * 2 + 1] = Pr * m1r - Pi * m1i;
            ai[h * 2 + 1] = Pr * m1i + Pi * m1r;
        }
    }

    // ---- CRZ ring fused into one diagonal phase per amp ----
    // pairs (ctrl bit, tgt bit, w): (7,6,w0)(6,5,w1)(5,4,w2)(4,3,w3)(3,2,w4)(2,1,w5)(1,0,w6)(0,7,w7)
    {
        const float w0 = W[0], w1 = W[1], w2 = W[2], w3 = W[3];
        const float w4 = W[4], w5 = W[5], w6 = W[6], w7 = W[7];
        const int b7 = (s >> 3) & 1, b6 = (s >> 2) & 1, b5 = (s >> 1) & 1, b4 = s & 1;
        float phiS = 0.0f;
        phiS += b7 ? (b6 ? w0 : -w0) : 0.0f;
        phiS += b6 ? (b5 ? w1 : -w1) : 0.0f;
        phiS += b5 ? (b4 ? w2 : -w2) : 0.0f;
        const float term3 = b4 ? w3 : 0.0f;   // pair (4,3): sign by r bit3
        const float term7 = b7 ? w7 : -w7;    // pair (0,7): added when r bit0 = 1
#pragma unroll
        for (int r = 0; r < 16; ++r) {
            const int b3 = (r >> 3) & 1, b2 = (r >> 2) & 1, b1 = (r >> 1) & 1, b0 = r & 1;
            float phi = phiS + (b3 ? term3 : -term3);
            if (b3) phi += b2 ? w4 : -w4;
            if (b2) phi += b1 ? w5 : -w5;
            if (b1) phi += b0 ? w6 : -w6;
            if (b0) phi += term7;
            float sp, cp;
            __sincosf(0.5f * phi, &sp, &cp);
            const float nr = ar[r] * cp - ai[r] * sp;
            const float ni = ar[r] * sp + ai[r] * cp;
            ar[r] = nr; ai[r] = ni;
        }
    }

    // ---- 56 CRX gates in reference order ----
#pragma unroll
    for (int i = 0; i < 8; ++i) {
#pragma unroll
        for (int j = 0; j < 8; ++j) {
            if (j == i) continue;
            const int gi = i * 7 + (j < i ? j : j - 1);
            const float c = rlane(gcv, gi);
            const float sn = rlane(gsv, gi);
            const int pc = 7 - i, pt = 7 - j;
            float ce, se;
            if (pc >= 4) {  // control is a sublane bit: fold into coefficients
                const int ctrl = (s >> (pc - 4)) & 1;
                ce = ctrl ? c : 1.0f;
                se = ctrl ? sn : 0.0f;
            } else {        // control is a reg bit: honest half-work
                ce = c; se = sn;
            }
            if (pt >= 4) {  // target across sublanes: DPP xor exchange
                const int ms = 1 << (pt - 4);
#pragma unroll
                for (int r = 0; r < 16; ++r) {
                    if (pc < 4 && !((r >> pc) & 1)) continue;
                    float prr, pii;
                    if (ms == 1)      { prr = xor1f(ar[r]); pii = xor1f(ai[r]); }
                    else if (ms == 2) { prr = xor2f(ar[r]); pii = xor2f(ai[r]); }
                    else if (ms == 4) { prr = xor4f(ar[r]); pii = xor4f(ai[r]); }
                    else              { prr = xor8f(ar[r]); pii = xor8f(ai[r]); }
                    ar[r] = ce * ar[r] + se * pii;
                    ai[r] = ce * ai[r] - se * prr;
                }
            } else {        // target is a reg bit: in-register pair update
                const int mt = 1 << pt;
#pragma unroll
                for (int r = 0; r < 16; ++r) {
                    if (r & mt) continue;
                    if (pc < 4 && !((r >> pc) & 1)) continue;
                    const int rp = r | mt;
                    const float tr = ar[r],  ti = ai[r];
                    const float ur = ar[rp], ui = ai[rp];
                    ar[r]  = ce * tr + se * ui;
                    ai[r]  = ce * ti - se * ur;
                    ar[rp] = ce * ur + se * ti;
                    ai[rp] = ce * ui - se * tr;
                }
            }
        }
    }

    // ---- probabilities + all 8 <Z_q> ----
    float p[16];
#pragma unroll
    for (int r = 0; r < 16; ++r) p[r] = ar[r] * ar[r] + ai[r] * ai[r];
    // in-lane tree over r bits: bit0->q7, bit1->q6, bit2->q5, bit3->q4
    float s8[8], E7 = 0.0f;
#pragma unroll
    for (int k = 0; k < 8; ++k) { s8[k] = p[2 * k] + p[2 * k + 1]; E7 += p[2 * k] - p[2 * k + 1]; }
    float s4[4], E6 = 0.0f;
#pragma unroll
    for (int k = 0; k < 4; ++k) { s4[k] = s8[2 * k] + s8[2 * k + 1]; E6 += s8[2 * k] - s8[2 * k + 1]; }
    float s2a[2], E5 = 0.0f;
#pragma unroll
    for (int k = 0; k < 2; ++k) { s2a[k] = s4[2 * k] + s4[2 * k + 1]; E5 += s4[2 * k] - s4[2 * k + 1]; }
    float A  = s2a[0] + s2a[1];
    float E4 = s2a[0] - s2a[1];
    // cross-sublane signed butterfly over s bits l (qubit 3-l), all DPP
    float D0, D1, D2, D3;
    { const float t = xor1f(A); D0 = A - t; A += t;
      E4 += xor1f(E4); E5 += xor1f(E5); E6 += xor1f(E6); E7 += xor1f(E7); }
    { const float t = xor2f(A); D1 = A - t; A += t;
      D0 += xor2f(D0);
      E4 += xor2f(E4); E5 += xor2f(E5); E6 += xor2f(E6); E7 += xor2f(E7); }
    { const float t = xor4f(A); D2 = A - t; A += t;
      D0 += xor4f(D0); D1 += xor4f(D1);
      E4 += xor4f(E4); E5 += xor4f(E5); E6 += xor4f(E6); E7 += xor4f(E7); }
    { const float t = xor8f(A); D3 = A - t;
      D0 += xor8f(D0); D1 += xor8f(D1); D2 += xor8f(D2);
      E4 += xor8f(E4); E5 += xor8f(E5); E6 += xor8f(E6); E7 += xor8f(E7); }

    if (s == 0 && active) {
        const float sc = 1.0f / 256.0f;  // (1/sqrt2)^8 squared, folded out of u's
        float* o = out + b * 8;
        o[0] = D3 * sc;  // qubit0 <- s bit3
        o[1] = D2 * sc;
        o[2] = D1 * sc;
        o[3] = D0 * sc;
        o[4] = E4 * sc;  // qubit4 <- r bit3
        o[5] = E5 * sc;
        o[6] = E6 * sc;
        o[7] = E7 * sc;
    }
}

extern "C" void kernel_launch(void* const* d_in, const int* in_sizes, int n_in,
                              void* d_out, int out_size, void* d_ws, size_t ws_size,
                              hipStream_t stream) {
    const float* X = (const float*)d_in[0];
    const float* W = (const float*)d_in[1];
    float* out = (float*)d_out;
    const int B = in_sizes[0] / 16;       // 2*N floats per row
    const int blocks = (B + 15) / 16;     // 4 waves x 4 elements per 256-thread block
    qsim_kernel<<<blocks, 256, 0, stream>>>(X, W, out, B);
}

// Round 4
// 78.063 us; speedup vs baseline: 1.3986x; 1.0015x over previous
//
#include <hip/hip_runtime.h>

// 8-qubit batched statevector sim, v4: all-register-controlled CRX.
//   16 lanes per element (sublane s = lane&15), 16 regs per lane, 4 elems/wave.
// Phase A layout L1: amp idx = r*16 + s  (idx bits 0..3 = s bits, 4..7 = r bits)
//   qubits 0..3 -> r bits 3..0 ; qubits 4..7 -> s bits 3..0.
//   CRX groups i=0..3 have ctrl = reg bit (only ctrl=1 regs touched).
// Then a 16x16 DPP xor-swap transpose to layout L2: amp idx = s*16 + r
//   (qubits 0..3 -> s bits 3..0 ; qubits 4..7 -> r bits 3..0), groups i=4..7
//   also reg-controlled. Epilogue identical to verified v3.
// All cross-lane via DPP (row-local): xor1=quad_perm[1,0,3,2], xor2=quad_perm[2,3,0,1],
// xor4=half_mirror(l^7) o quad_perm[3,2,1,0](l^3), xor8=row_ror:8.

static __device__ __forceinline__ float rlane(float v, int src) {
    return __int_as_float(__builtin_amdgcn_readlane(__float_as_int(v), src));
}
template <int CTRL>
static __device__ __forceinline__ float dppf(float x) {
    return __int_as_float(__builtin_amdgcn_update_dpp(0, __float_as_int(x), CTRL, 0xF, 0xF, true));
}
static __device__ __forceinline__ float xor1f(float x) { return dppf<0xB1>(x); }
static __device__ __forceinline__ float xor2f(float x) { return dppf<0x4E>(x); }
static __device__ __forceinline__ float xor4f(float x) { return dppf<0x1B>(dppf<0x141>(x)); }
static __device__ __forceinline__ float xor8f(float x) { return dppf<0x128>(x); }
static __device__ __forceinline__ float xorMf(float x, int m) {  // m compile-time after unroll
    if (m == 1) return xor1f(x);
    if (m == 2) return xor2f(x);
    if (m == 4) return xor4f(x);
    return xor8f(x);
}

__global__ __launch_bounds__(256, 4) void qsim_kernel(const float* __restrict__ X,
                                                      const float* __restrict__ W,
                                                      float* __restrict__ out,
                                                      int B) {
    const int lane = threadIdx.x & 63;
    const int g = lane >> 4;   // element slot in wave
    const int s = lane & 15;   // sublane within element
    const int b = (blockIdx.x * 4 + (threadIdx.x >> 6)) * 4 + g;
    const bool active = (b < B);
    const int bc = active ? b : (B - 1);   // clamp loads; keep all lanes alive for DPP

    // ---- CRX trig: lane gi (<56) holds cos/sin of 0.5*W[1+i, j] (wave-shared) ----
    float gcv = 1.0f, gsv = 0.0f;
    if (lane < 56) {
        const int i = lane / 7;
        const int jj = lane - 7 * i;
        const int j = jj + (jj >= i ? 1 : 0);
        const float h = 0.5f * W[(1 + i) * 72 + j];
        __sincosf(h, &gsv, &gcv);
    }

    // ---- per-qubit fused H->RZ->RY first column (sublane q computes qubit q) ----
    float u0r, u0i, u1r, u1i;
    {
        const int q = s & 7;
        float2 xq = ((const float2*)X)[bc * 8 + q];
        float cz, sz, cy, sy;
        __sincosf(0.5f * xq.x, &sz, &cz);
        __sincosf(0.5f * xq.y, &sy, &cy);
        u0r = (cy - sy) * cz;  u0i = -(cy + sy) * sz;
        u1r = (cy + sy) * cz;  u1i = (cy - sy) * sz;
    }

    // ---- product state in L1 ----
    // lane part: qubits 4..7 -> s bits 3..0
    float Pr = 1.0f, Pi = 0.0f;
#pragma unroll
    for (int q = 4; q < 8; ++q) {
        const int src = (g << 4) + q;
        const float a0r = __shfl(u0r, src, 64), a0i = __shfl(u0i, src, 64);
        const float a1r = __shfl(u1r, src, 64), a1i = __shfl(u1i, src, 64);
        const int bit = (s >> (7 - q)) & 1;
        const float vr = bit ? a1r : a0r;
        const float vi = bit ? a1i : a0i;
        const float nr = Pr * vr - Pi * vi;
        const float ni = Pr * vi + Pi * vr;
        Pr = nr; Pi = ni;
    }
    // reg part: qubits 0..3 -> r bits 3..0
    float w0r[4], w0i[4], w1r[4], w1i[4];
#pragma unroll
    for (int k = 0; k < 4; ++k) {
        const int src = (g << 4) + k;
        w0r[k] = __shfl(u0r, src, 64);  w0i[k] = __shfl(u0i, src, 64);
        w1r[k] = __shfl(u1r, src, 64);  w1i[k] = __shfl(u1i, src, 64);
    }
    float ar[16], ai[16];
    {
        // doubling over r bits 3,2,1,0 (qubits 0,1,2,3)
        float t1r[2], t1i[2];
        t1r[0] = w0r[0]; t1i[0] = w0i[0];
        t1r[1] = w1r[0]; t1i[1] = w1i[0];
        float t2r[4], t2i[4];
#pragma unroll
        for (int h = 0; h < 2; ++h) {
            t2r[h * 2 + 0] = t1r[h] * w0r[1] - t1i[h] * w0i[1];
            t2i[h * 2 + 0] = t1r[h] * w0i[1] + t1i[h] * w0r[1];
            t2r[h * 2 + 1] = t1r[h] * w1r[1] - t1i[h] * w1i[1];
            t2i[h * 2 + 1] = t1r[h] * w1i[1] + t1i[h] * w1r[1];
        }
        float t3r[8], t3i[8];
#pragma unroll
        for (int h = 0; h < 4; ++h) {
            t3r[h * 2 + 0] = t2r[h] * w0r[2] - t2i[h] * w0i[2];
            t3i[h * 2 + 0] = t2r[h] * w0i[2] + t2i[h] * w0r[2];
            t3r[h * 2 + 1] = t2r[h] * w1r[2] - t2i[h] * w1i[2];
            t3i[h * 2 + 1] = t2r[h] * w1i[2] + t2i[h] * w1r[2];
        }
#pragma unroll
        for (int h = 0; h < 8; ++h) {
            const float m0r = t3r[h] * w0r[3] - t3i[h] * w0i[3];
            const float m0i = t3r[h] * w0i[3] + t3i[h] * w0r[3];
            const float m1r = t3r[h] * w1r[3] - t3i[h] * w1i[3];
            const float m1i = t3r[h] * w1i[3] + t3i[h] * w1r[3];
            ar[h * 2 + 0] = Pr * m0r - Pi * m0i;
            ai[h * 2 + 0] = Pr * m0i + Pi * m0r;
            ar[h * 2 + 1] = Pr * m1r - Pi * m1i;
            ai[h * 2 + 1] = Pr * m1i + Pi * m1r;
        }
    }

    // ---- CRZ ring fused into one diagonal phase per amp (L1 bit mapping) ----
    // idx-bit pairs: (7,6,w0)(6,5,w1)(5,4,w2)(4,3,w3)(3,2,w4)(2,1,w5)(1,0,w6)(0,7,w7)
    // L1: bits 7..4 = r bits 3..0 ; bits 3..0 = s bits 3..0.
    {
        const float w0 = W[0], w1 = W[1], w2 = W[2], w3 = W[3];
        const float w4 = W[4], w5 = W[5], w6 = W[6], w7 = W[7];
        const int s3 = (s >> 3) & 1, s2 = (s >> 2) & 1, s1 = (s >> 1) & 1, s0 = s & 1;
        float phiS = 0.0f;
        phiS += s3 ? (s2 ? w4 : -w4) : 0.0f;
        phiS += s2 ? (s1 ? w5 : -w5) : 0.0f;
        phiS += s1 ? (s0 ? w6 : -w6) : 0.0f;
        const float termA = s3 ? w3 : -w3;   // pair (4,3): ctrl r0, sign by s3
        const float termB = s0 ? w7 : 0.0f;  // pair (0,7): ctrl s0, sign by r3
#pragma unroll
        for (int r = 0; r < 16; ++r) {
            const int b3 = (r >> 3) & 1, b2 = (r >> 2) & 1, b1 = (r >> 1) & 1, b0 = r & 1;
            float phi = phiS + (b3 ? termB : -termB);
            if (b3) phi += b2 ? w0 : -w0;
            if (b2) phi += b1 ? w1 : -w1;
            if (b1) phi += b0 ? w2 : -w2;
            if (b0) phi += termA;
            float sp, cp;
            __sincosf(0.5f * phi, &sp, &cp);
            const float nr = ar[r] * cp - ai[r] * sp;
            const float ni = ar[r] * sp + ai[r] * cp;
            ar[r] = nr; ai[r] = ni;
        }
    }

    // ---- CRX phase A: groups i=0..3 in L1 (ctrl = reg bit 3-i) ----
#pragma unroll
    for (int i = 0; i < 4; ++i) {
        float cg[8], sg[8];
#pragma unroll
        for (int j = 0; j < 8; ++j) {
            if (j == i) continue;
            const int gi = i * 7 + (j < i ? j : j - 1);
            cg[j] = rlane(gcv, gi);
            sg[j] = rlane(gsv, gi);
        }
        const int rc = 3 - i;
#pragma unroll
        for (int j = 0; j < 8; ++j) {
            if (j == i) continue;
            if (j < 4) {  // reg target bit (3-j): pair update on ctrl=1 regs
                const int mt = 1 << (3 - j);
#pragma unroll
                for (int r = 0; r < 16; ++r) {
                    if (!((r >> rc) & 1)) continue;
                    if (r & mt) continue;
                    const int rp = r | mt;
                    const float tr = ar[r],  ti = ai[r];
                    const float ur = ar[rp], ui = ai[rp];
                    ar[r]  = cg[j] * tr + sg[j] * ui;
                    ai[r]  = cg[j] * ti - sg[j] * ur;
                    ar[rp] = cg[j] * ur + sg[j] * ti;
                    ai[rp] = cg[j] * ui - sg[j] * tr;
                }
            } else {      // lane target: s bit (7-j) -> DPP xor(1<<(7-j))
                const int ms = 1 << (7 - j);
#pragma unroll
                for (int r = 0; r < 16; ++r) {
                    if (!((r >> rc) & 1)) continue;
                    const float prr = xorMf(ar[r], ms);
                    const float pii = xorMf(ai[r], ms);
                    ar[r] = cg[j] * ar[r] + sg[j] * pii;
                    ai[r] = cg[j] * ai[r] - sg[j] * prr;
                }
            }
        }
    }

    // ---- 16x16 transpose L1 -> L2 via xor-swap stages (k = 1,2,4,8) ----
    // new[s][r] = old[r][s]:  stage k swaps a[s][r] <-> a[s^k][r^k] where (s&k)!=(r&k).
#pragma unroll
    for (int k = 1; k <= 8; k <<= 1) {
        const bool sk = (s & k) != 0;
#pragma unroll
        for (int r = 0; r < 16; ++r) {
            if (r & k) continue;
            const int rp = r | k;
            const float tpr = xorMf(ar[rp], k), tpi = xorMf(ai[rp], k);
            const float trr = xorMf(ar[r],  k), tri = xorMf(ai[r],  k);
            ar[r]  = sk ? tpr : ar[r];
            ai[r]  = sk ? tpi : ai[r];
            ar[rp] = sk ? ar[rp] : trr;
            ai[rp] = sk ? ai[rp] : tri;
        }
    }

    // ---- CRX phase B: groups i=4..7 in L2 (ctrl = reg bit 7-i) ----
#pragma unroll
    for (int i = 4; i < 8; ++i) {
        float cg[8], sg[8];
#pragma unroll
        for (int j = 0; j < 8; ++j) {
            if (j == i) continue;
            const int gi = i * 7 + (j < i ? j : j - 1);
            cg[j] = rlane(gcv, gi);
            sg[j] = rlane(gsv, gi);
        }
        const int rc = 7 - i;
#pragma unroll
        for (int j = 0; j < 8; ++j) {
            if (j == i) continue;
            if (j < 4) {  // lane target: s bit (3-j) -> DPP xor(1<<(3-j))
                const int ms = 1 << (3 - j);
#pragma unroll
                for (int r = 0; r < 16; ++r) {
                    if (!((r >> rc) & 1)) continue;
                    const float prr = xorMf(ar[r], ms);
                    const float pii = xorMf(ai[r], ms);
                    ar[r] = cg[j] * ar[r] + sg[j] * pii;
                    ai[r] = cg[j] * ai[r] - sg[j] * prr;
                }
            } else {      // reg target bit (7-j)
                const int mt = 1 << (7 - j);
#pragma unroll
                for (int r = 0; r < 16; ++r) {
                    if (!((r >> rc) & 1)) continue;
                    if (r & mt) continue;
                    const int rp = r | mt;
                    const float tr = ar[r],  ti = ai[r];
                    const float ur = ar[rp], ui = ai[rp];
                    ar[r]  = cg[j] * tr + sg[j] * ui;
                    ai[r]  = cg[j] * ti - sg[j] * ur;
                    ar[rp] = cg[j] * ur + sg[j] * ti;
                    ai[rp] = cg[j] * ui - sg[j] * tr;
                }
            }
        }
    }

    // ---- probabilities + all 8 <Z_q>  (L2: r bits 0..3 = qubits 7..4, s bits = q3..q0) ----
    float p[16];
#pragma unroll
    for (int r = 0; r < 16; ++r) p[r] = ar[r] * ar[r] + ai[r] * ai[r];
    float s8[8], E7 = 0.0f;
#pragma unroll
    for (int k = 0; k < 8; ++k) { s8[k] = p[2 * k] + p[2 * k + 1]; E7 += p[2 * k] - p[2 * k + 1]; }
    float s4[4], E6 = 0.0f;
#pragma unroll
    for (int k = 0; k < 4; ++k) { s4[k] = s8[2 * k] + s8[2 * k + 1]; E6 += s8[2 * k] - s8[2 * k + 1]; }
    float s2a[2], E5 = 0.0f;
#pragma unroll
    for (int k = 0; k < 2; ++k) { s2a[k] = s4[2 * k] + s4[2 * k + 1]; E5 += s4[2 * k] - s4[2 * k + 1]; }
    float A  = s2a[0] + s2a[1];
    float E4 = s2a[0] - s2a[1];
    float D0, D1, D2, D3;
    { const float t = xor1f(A); D0 = A - t; A += t;
      E4 += xor1f(E4); E5 += xor1f(E5); E6 += xor1f(E6); E7 += xor1f(E7); }
    { const float t = xor2f(A); D1 = A - t; A += t;
      D0 += xor2f(D0);
      E4 += xor2f(E4); E5 += xor2f(E5); E6 += xor2f(E6); E7 += xor2f(E7); }
    { const float t = xor4f(A); D2 = A - t; A += t;
      D0 += xor4f(D0); D1 += xor4f(D1);
      E4 += xor4f(E4); E5 += xor4f(E5); E6 += xor4f(E6); E7 += xor4f(E7); }
    { const float t = xor8f(A); D3 = A - t;
      D0 += xor8f(D0); D1 += xor8f(D1); D2 += xor8f(D2);
      E4 += xor8f(E4); E5 += xor8f(E5); E6 += xor8f(E6); E7 += xor8f(E7); }

    if (s == 0 && active) {
        const float sc = 1.0f / 256.0f;  // (1/sqrt2)^8 squared, folded out of u's
        float* o = out + b * 8;
        o[0] = D3 * sc;
        o[1] = D2 * sc;
        o[2] = D1 * sc;
        o[3] = D0 * sc;
        o[4] = E4 * sc;
        o[5] = E5 * sc;
        o[6] = E6 * sc;
        o[7] = E7 * sc;
    }
}

extern "C" void kernel_launch(void* const* d_in, const int* in_sizes, int n_in,
                              void* d_out, int out_size, void* d_ws, size_t ws_size,
                              hipStream_t stream) {
    const float* X = (const float*)d_in[0];
    const float* W = (const float*)d_in[1];
    float* out = (float*)d_out;
    const int B = in_sizes[0] / 16;       // 2*N floats per row
    const int blocks = (B + 15) / 16;     // 4 waves x 4 elements per 256-thread block
    qsim_kernel<<<blocks, 256, 0, stream>>>(X, W, out, B);
}

// Round 5
// 76.855 us; speedup vs baseline: 1.4205x; 1.0157x over previous
//
#include <hip/hip_runtime.h>

// 8-qubit batched statevector sim, v5: v4 structure with float2 (packed-fp32) state.
//   16 lanes per element (sublane s = lane&15), 16 float2 regs per lane, 4 elems/wave.
// Phase A layout L1: amp idx = r*16 + s ; qubits 0..3 -> r bits 3..0, 4..7 -> s bits 3..0.
// Then 16x16 DPP xor-swap transpose to L2: amp idx = s*16 + r ; groups i=4..7 reg-ctrl.
// All cross-lane via DPP: xor1=quad_perm[1,0,3,2], xor2=quad_perm[2,3,0,1],
// xor4=half_mirror o quad_perm[3,2,1,0], xor8=row_ror:8.
// Gate update c*t + s*(u.y,-u.x) is the v_pk_mul/v_pk_fma op_sel/neg_hi pattern.

static __device__ __forceinline__ float rlane(float v, int src) {
    return __int_as_float(__builtin_amdgcn_readlane(__float_as_int(v), src));
}
template <int CTRL>
static __device__ __forceinline__ float dppf(float x) {
    return __int_as_float(__builtin_amdgcn_update_dpp(0, __float_as_int(x), CTRL, 0xF, 0xF, true));
}
static __device__ __forceinline__ float xor1f(float x) { return dppf<0xB1>(x); }
static __device__ __forceinline__ float xor2f(float x) { return dppf<0x4E>(x); }
static __device__ __forceinline__ float xor4f(float x) { return dppf<0x1B>(dppf<0x141>(x)); }
static __device__ __forceinline__ float xor8f(float x) { return dppf<0x128>(x); }
static __device__ __forceinline__ float xorMf(float x, int m) {  // m compile-time after unroll
    if (m == 1) return xor1f(x);
    if (m == 2) return xor2f(x);
    if (m == 4) return xor4f(x);
    return xor8f(x);
}
static __device__ __forceinline__ float2 xorM2(float2 a, int m) {
    float2 t; t.x = xorMf(a.x, m); t.y = xorMf(a.y, m); return t;
}
// complex multiply
static __device__ __forceinline__ float2 cmul(float2 a, float2 b) {
    float2 t;
    t.x = a.x * b.x - a.y * b.y;
    t.y = a.x * b.y + a.y * b.x;
    return t;
}
// CRX half-rotation: c*t + s*(u.y, -u.x)   (packed: pk_mul(op_sel swap) + pk_fma(neg_hi))
static __device__ __forceinline__ float2 rotA(float2 t, float2 u, float c, float s) {
    float2 d;
    d.x = c * t.x + s * u.y;
    d.y = c * t.y - s * u.x;
    return d;
}

__global__ __launch_bounds__(256, 4) void qsim_kernel(const float* __restrict__ X,
                                                      const float* __restrict__ W,
                                                      float* __restrict__ out,
                                                      int B) {
    const int lane = threadIdx.x & 63;
    const int g = lane >> 4;   // element slot in wave
    const int s = lane & 15;   // sublane within element
    const int b = (blockIdx.x * 4 + (threadIdx.x >> 6)) * 4 + g;
    const bool active = (b < B);
    const int bc = active ? b : (B - 1);   // clamp loads; keep all lanes alive for DPP

    // ---- CRX trig: lane gi (<56) holds cos/sin of 0.5*W[1+i, j] (wave-shared) ----
    float gcv = 1.0f, gsv = 0.0f;
    if (lane < 56) {
        const int i = lane / 7;
        const int jj = lane - 7 * i;
        const int j = jj + (jj >= i ? 1 : 0);
        const float h = 0.5f * W[(1 + i) * 72 + j];
        __sincosf(h, &gsv, &gcv);
    }

    // ---- per-qubit fused H->RZ->RY first column (sublane q computes qubit q) ----
    float u0r, u0i, u1r, u1i;
    {
        const int q = s & 7;
        float2 xq = ((const float2*)X)[bc * 8 + q];
        float cz, sz, cy, sy;
        __sincosf(0.5f * xq.x, &sz, &cz);
        __sincosf(0.5f * xq.y, &sy, &cy);
        u0r = (cy - sy) * cz;  u0i = -(cy + sy) * sz;
        u1r = (cy + sy) * cz;  u1i = (cy - sy) * sz;
    }

    // ---- product state in L1 ----
    // lane part: qubits 4..7 -> s bits 3..0
    float2 P; P.x = 1.0f; P.y = 0.0f;
#pragma unroll
    for (int q = 4; q < 8; ++q) {
        const int src = (g << 4) + q;
        const float a0r = __shfl(u0r, src, 64), a0i = __shfl(u0i, src, 64);
        const float a1r = __shfl(u1r, src, 64), a1i = __shfl(u1i, src, 64);
        const int bit = (s >> (7 - q)) & 1;
        float2 v; v.x = bit ? a1r : a0r; v.y = bit ? a1i : a0i;
        P = cmul(P, v);
    }
    // reg part: qubits 0..3 -> r bits 3..0
    float2 w0[4], w1[4];
#pragma unroll
    for (int k = 0; k < 4; ++k) {
        const int src = (g << 4) + k;
        w0[k].x = __shfl(u0r, src, 64);  w0[k].y = __shfl(u0i, src, 64);
        w1[k].x = __shfl(u1r, src, 64);  w1[k].y = __shfl(u1i, src, 64);
    }
    float2 a[16];
    {
        // doubling over r bits 3,2,1,0 (qubits 0,1,2,3)
        float2 t1[2];
        t1[0] = w0[0];
        t1[1] = w1[0];
        float2 t2[4];
#pragma unroll
        for (int h = 0; h < 2; ++h) {
            t2[h * 2 + 0] = cmul(t1[h], w0[1]);
            t2[h * 2 + 1] = cmul(t1[h], w1[1]);
        }
        float2 t3[8];
#pragma unroll
        for (int h = 0; h < 4; ++h) {
            t3[h * 2 + 0] = cmul(t2[h], w0[2]);
            t3[h * 2 + 1] = cmul(t2[h], w1[2]);
        }
#pragma unroll
        for (int h = 0; h < 8; ++h) {
            a[h * 2 + 0] = cmul(P, cmul(t3[h], w0[3]));
            a[h * 2 + 1] = cmul(P, cmul(t3[h], w1[3]));
        }
    }

    // ---- CRZ ring fused into one diagonal phase per amp (L1 bit mapping) ----
    // idx-bit pairs: (7,6,w0)(6,5,w1)(5,4,w2)(4,3,w3)(3,2,w4)(2,1,w5)(1,0,w6)(0,7,w7)
    // L1: bits 7..4 = r bits 3..0 ; bits 3..0 = s bits 3..0.
    {
        const float wv0 = W[0], wv1 = W[1], wv2 = W[2], wv3 = W[3];
        const float wv4 = W[4], wv5 = W[5], wv6 = W[6], wv7 = W[7];
        const int s3 = (s >> 3) & 1, s2 = (s >> 2) & 1, s1 = (s >> 1) & 1, s0 = s & 1;
        float phiS = 0.0f;
        phiS += s3 ? (s2 ? wv4 : -wv4) : 0.0f;
        phiS += s2 ? (s1 ? wv5 : -wv5) : 0.0f;
        phiS += s1 ? (s0 ? wv6 : -wv6) : 0.0f;
        const float termA = s3 ? wv3 : -wv3;   // pair (4,3): ctrl r0, sign by s3
        const float termB = s0 ? wv7 : 0.0f;   // pair (0,7): ctrl s0, sign by r3
#pragma unroll
        for (int r = 0; r < 16; ++r) {
            const int b3 = (r >> 3) & 1, b2 = (r >> 2) & 1, b1 = (r >> 1) & 1, b0 = r & 1;
            float phi = phiS + (b3 ? termB : -termB);
            if (b3) phi += b2 ? wv0 : -wv0;
            if (b2) phi += b1 ? wv1 : -wv1;
            if (b1) phi += b0 ? wv2 : -wv2;
            if (b0) phi += termA;
            float2 ph;
            __sincosf(0.5f * phi, &ph.y, &ph.x);
            a[r] = cmul(a[r], ph);
        }
    }

    // ---- CRX phase A: groups i=0..3 in L1 (ctrl = reg bit 3-i) ----
#pragma unroll
    for (int i = 0; i < 4; ++i) {
        float cg[8], sg[8];
#pragma unroll
        for (int j = 0; j < 8; ++j) {
            if (j == i) continue;
            const int gi = i * 7 + (j < i ? j : j - 1);
            cg[j] = rlane(gcv, gi);
            sg[j] = rlane(gsv, gi);
        }
        const int rc = 3 - i;
#pragma unroll
        for (int j = 0; j < 8; ++j) {
            if (j == i) continue;
            if (j < 4) {  // reg target bit (3-j): pair update on ctrl=1 regs
                const int mt = 1 << (3 - j);
#pragma unroll
                for (int r = 0; r < 16; ++r) {
                    if (!((r >> rc) & 1)) continue;
                    if (r & mt) continue;
                    const int rp = r | mt;
                    const float2 t = a[r], u = a[rp];
                    a[r]  = rotA(t, u, cg[j], sg[j]);
                    a[rp] = rotA(u, t, cg[j], sg[j]);
                }
            } else {      // lane target: s bit (7-j) -> DPP xor(1<<(7-j))
                const int ms = 1 << (7 - j);
#pragma unroll
                for (int r = 0; r < 16; ++r) {
                    if (!((r >> rc) & 1)) continue;
                    const float2 p = xorM2(a[r], ms);
                    a[r] = rotA(a[r], p, cg[j], sg[j]);
                }
            }
        }
    }

    // ---- 16x16 transpose L1 -> L2 via xor-swap stages (k = 1,2,4,8) ----
#pragma unroll
    for (int k = 1; k <= 8; k <<= 1) {
        const bool sk = (s & k) != 0;
#pragma unroll
        for (int r = 0; r < 16; ++r) {
            if (r & k) continue;
            const int rp = r | k;
            const float2 tp = xorM2(a[rp], k);
            const float2 tr = xorM2(a[r],  k);
            a[r].x  = sk ? tp.x : a[r].x;
            a[r].y  = sk ? tp.y : a[r].y;
            a[rp].x = sk ? a[rp].x : tr.x;
            a[rp].y = sk ? a[rp].y : tr.y;
        }
    }

    // ---- CRX phase B: groups i=4..7 in L2 (ctrl = reg bit 7-i) ----
#pragma unroll
    for (int i = 4; i < 8; ++i) {
        float cg[8], sg[8];
#pragma unroll
        for (int j = 0; j < 8; ++j) {
            if (j == i) continue;
            const int gi = i * 7 + (j < i ? j : j - 1);
            cg[j] = rlane(gcv, gi);
            sg[j] = rlane(gsv, gi);
        }
        const int rc = 7 - i;
#pragma unroll
        for (int j = 0; j < 8; ++j) {
            if (j == i) continue;
            if (j < 4) {  // lane target: s bit (3-j) -> DPP xor(1<<(3-j))
                const int ms = 1 << (3 - j);
#pragma unroll
                for (int r = 0; r < 16; ++r) {
                    if (!((r >> rc) & 1)) continue;
                    const float2 p = xorM2(a[r], ms);
                    a[r] = rotA(a[r], p, cg[j], sg[j]);
                }
            } else {      // reg target bit (7-j)
                const int mt = 1 << (7 - j);
#pragma unroll
                for (int r = 0; r < 16; ++r) {
                    if (!((r >> rc) & 1)) continue;
                    if (r & mt) continue;
                    const int rp = r | mt;
                    const float2 t = a[r], u = a[rp];
                    a[r]  = rotA(t, u, cg[j], sg[j]);
                    a[rp] = rotA(u, t, cg[j], sg[j]);
                }
            }
        }
    }

    // ---- probabilities + all 8 <Z_q>  (L2: r bits 3..0 = qubits 4..7, s bits 3..0 = q0..q3) ----
    float p[16];
#pragma unroll
    for (int r = 0; r < 16; ++r) p[r] = a[r].x * a[r].x + a[r].y * a[r].y;
    float s8[8], E7 = 0.0f;
#pragma unroll
    for (int k = 0; k < 8; ++k) { s8[k] = p[2 * k] + p[2 * k + 1]; E7 += p[2 * k] - p[2 * k + 1]; }
    float s4[4], E6 = 0.0f;
#pragma unroll
    for (int k = 0; k < 4; ++k) { s4[k] = s8[2 * k] + s8[2 * k + 1]; E6 += s8[2 * k] - s8[2 * k + 1]; }
    float s2a[2], E5 = 0.0f;
#pragma unroll
    for (int k = 0; k < 2; ++k) { s2a[k] = s4[2 * k] + s4[2 * k + 1]; E5 += s4[2 * k] - s4[2 * k + 1]; }
    float A  = s2a[0] + s2a[1];
    float E4 = s2a[0] - s2a[1];
    float D0, D1, D2, D3;
    { const float t = xor1f(A); D0 = A - t; A += t;
      E4 += xor1f(E4); E5 += xor1f(E5); E6 += xor1f(E6); E7 += xor1f(E7); }
    { const float t = xor2f(A); D1 = A - t; A += t;
      D0 += xor2f(D0);
      E4 += xor2f(E4); E5 += xor2f(E5); E6 += xor2f(E6); E7 += xor2f(E7); }
    { const float t = xor4f(A); D2 = A - t; A += t;
      D0 += xor4f(D0); D1 += xor4f(D1);
      E4 += xor4f(E4); E5 += xor4f(E5); E6 += xor4f(E6); E7 += xor4f(E7); }
    { const float t = xor8f(A); D3 = A - t;
      D0 += xor8f(D0); D1 += xor8f(D1); D2 += xor8f(D2);
      E4 += xor8f(E4); E5 += xor8f(E5); E6 += xor8f(E6); E7 += xor8f(E7); }

    if (s == 0 && active) {
        const float sc = 1.0f / 256.0f;  // (1/sqrt2)^8 squared, folded out of u's
        float* o = out + b * 8;
        o[0] = D3 * sc;
        o[1] = D2 * sc;
        o[2] = D1 * sc;
        o[3] = D0 * sc;
        o[4] = E4 * sc;
        o[5] = E5 * sc;
        o[6] = E6 * sc;
        o[7] = E7 * sc;
    }
}

extern "C" void kernel_launch(void* const* d_in, const int* in_sizes, int n_in,
                              void* d_out, int out_size, void* d_ws, size_t ws_size,
                              hipStream_t stream) {
    const float* X = (const float*)d_in[0];
    const float* W = (const float*)d_in[1];
    float* out = (float*)d_out;
    const int B = in_sizes[0] / 16;       // 2*N floats per row
    const int blocks = (B + 15) / 16;     // 4 waves x 4 elements per 256-thread block
    qsim_kernel<<<blocks, 256, 0, stream>>>(X, W, out, B);
}